// Round 11
// baseline (135.787 us; speedup 1.0000x reference)
//
#include <hip/hip_runtime.h>

// Correlation via bf16 MFMA banded Gram.
// out[b, dyp*21+k, y, x] = (1/256) * sum_c in1[b,c,y,x] * in2[b,c,y+2(dyp-10), x+2(k-10)]
// Layouts (workspace): Ag/Bg[b*64+y][par*48+col][c] bf16, x = 2*col+par.
//
// R16 = R15 + (a) inline-asm counted-vmcnt A-pipeline, (b) par co-location.
// R15 evidence: VGPR=60 -> compiler flattened the rotating prefetch (3rd time);
// per-step A-load latency exposed 24x/round. Fix: asm global_load_dwordx4 x12
// in flight, consumed under s_waitcnt vmcnt(9..0) + sched_barrier(0) (rule #18).
// Counts are insertion-safe (extra compiler vmem ops only make waits stricter).
// WRITE was 70.8MB (2x): par-siblings stored half-lines from different XCDs.
// New chunk = b*2 + (y2>>5): par pairs co-resident on one XCD -> L2 write merge.
// Harness fact: 2x 42us fillBufferAligned (256MiB ws poison) = fixed 84us floor.
// (R17 resubmit: R16 bench was GPUAcquisitionTimeout; source unchanged.)

typedef short bf16x8 __attribute__((ext_vector_type(8)));
typedef float f32x4  __attribute__((ext_vector_type(4)));

#define PLANE 24576         // shorts per (b,y) plane: 96 rows * 256 c
#define ST    40            // prepass LDS row stride (shorts)

__device__ __forceinline__ short f2bf(float f) {
    union { float f; unsigned u; } x; x.f = f;
    const unsigned u = x.u;
    return (short)((u + 0x7fffu + ((u >> 16) & 1u)) >> 16);
}

// ---------- prepass: fp32 [b][c][y][x] -> bf16 [b*64+y][par*48+col][c] ----------
// block = (sel, b, ytile of 8, ctile of 32ch). Reads 3KB contiguous per channel.
__global__ __launch_bounds__(512)
void corr_prepass(const float* __restrict__ in1, const float* __restrict__ in2,
                  short* __restrict__ dstA, short* __restrict__ dstB) {
    const int bid = blockIdx.x;
    const int sel = bid >> 8;
    const int r   = bid & 255;
    const int b   = r >> 6;
    const int yt  = (r >> 3) & 7;
    const int ct  = r & 7;
    const int c0 = ct * 32, y0 = yt * 8;
    const float* src = sel ? in2 : in1;
    short* dst = sel ? dstB : dstA;

    __shared__ __align__(16) short T[768 * ST];   // [xx = yy*96+x][32c], 61.4 KB
    const int tid = threadIdx.x;

#pragma unroll
    for (int it = 0; it < 2; ++it) {
        const int d = it * 512 + tid;            // [0,1024), use d<768
        if (d < 768) {
            const int g = d / 192;               // channel octet 0..3
            const int f = d - g * 192;           // float4 index in 8y*96x chunk
            float4 v[8];
#pragma unroll
            for (int j = 0; j < 8; ++j) {
                const int c = c0 + g * 8 + j;
                v[j] = *(const float4*)(src + ((size_t)(b * 256 + c) * 64 + y0) * 96 + 4 * f);
            }
            bf16x8 w0, w1, w2, w3;
#pragma unroll
            for (int j = 0; j < 8; ++j) {
                w0[j] = f2bf(v[j].x); w1[j] = f2bf(v[j].y);
                w2[j] = f2bf(v[j].z); w3[j] = f2bf(v[j].w);
            }
            const int perm = ((g ^ (f & 3)) * 8);
            const int base = 4 * f * ST + perm;
            *(bf16x8*)&T[base]          = w0;
            *(bf16x8*)&T[base + ST]     = w1;
            *(bf16x8*)&T[base + 2*ST]   = w2;
            *(bf16x8*)&T[base + 3*ST]   = w3;
        }
    }
    __syncthreads();

#pragma unroll
    for (int it = 0; it < 6; ++it) {
        const int D  = it * 512 + tid;           // [0,3072)
        const int Rl = D >> 2, gp = D & 3;
        const int yy  = Rl / 96;
        const int rl  = Rl - yy * 96;
        const int par = rl / 48;
        const int col = rl - par * 48;
        const int x   = 2 * col + par;
        const int xx  = yy * 96 + x;
        const int perm = ((gp ^ ((xx >> 2) & 3)) * 8);
        const bf16x8 w = *(const bf16x8*)&T[xx * ST + perm];
        const size_t Rg = (size_t)(b * 64 + y0 + yy) * 96 + par * 48 + col;
        *(bf16x8*)(dst + Rg * 256 + c0 + gp * 8) = w;
    }
}

// asm A-load: 16B global load, immediate byte offset; dest regs pinned by asm.
#define GLOAD(dst, ptr, imm) \
    asm volatile("global_load_dwordx4 %0, %1, off offset:%c2" \
                 : "=&v"(dst) : "v"(ptr), "n"(imm))

// counted wait + hard scheduling fence (rule #18: MFMA must not hoist above)
#define WAITV(N) \
    asm volatile("s_waitcnt vmcnt(" #N ")"); \
    __builtin_amdgcn_sched_barrier(0)

// ---------- main kernel: 512 threads = 8 waves = 8 slots, single par ----------
// Barrier-free rounds; wave-private scr; dyp = p*8 + slot, p in [0,3).
__global__ __launch_bounds__(512, 2)
void corr_mfma(const short* __restrict__ Ag, const short* __restrict__ Bg,
               float* __restrict__ out) {
    // XCD chunk = (b, y2-half): par-siblings for the same output lines live on
    // the SAME XCD -> L2 merges the stride-2 half-line stores.
    const int bhw = blockIdx.x;                  // [0,512)
    const int bid = ((bhw & 7) << 6) | (bhw >> 3);
    const int chunk = bid >> 6;                  // = XCD, [0,8)
    const int b    = chunk >> 1;
    const int yhi  = chunk & 1;
    const int inner = bid & 63;
    const int par  = inner >> 5;
    const int y2   = (yhi << 5) | (inner & 31);
    const int by2  = b * 64 + y2;

    const int tid  = threadIdx.x;
    const int lane = tid & 63, slot = tid >> 6;  // slot in [0,8)
    const int n    = lane & 15, q = lane >> 4;

    __shared__ __align__(16) short Bsh[48 * 256];    // 24576 B, XOR-swizzled rows
    __shared__ __align__(16) float scr[8][1008];     // 32256 B, per-wave, xe-major

    // stage B(b,y2) par-half ONCE (swizzle: short_idx ^= (row&7)<<3)
    {
        const short* src = Bg + (size_t)by2 * PLANE + par * 48 * 256;
#pragma unroll
        for (int it = 0; it < 3; ++it) {
            const int j   = it * 512 + tid;      // [0,1536)
            const int row = j >> 5;              // [0,48)
            const int ofs = (row * 256 + (j & 31) * 8) ^ ((row & 7) << 3);
            *(bf16x8*)&Bsh[ofs] = *(const bf16x8*)(src + j * 8);
        }
    }
    __syncthreads();                             // the ONLY block-wide barrier

    const bool v0 = (n >= 10), v3 = (n < 10);
    const int r0 = v0 ? (n - 10) : 0;
    const int r1 = n + 6;
    const int r2 = n + 22;
    const int r3 = v3 ? (n + 38) : 0;            // all in [0,48)

    float* const sc = scr[slot];

#pragma unroll
    for (int p = 0; p < 3; ++p) {
        const int dyp = p * 8 + slot;
        const int y   = y2 + 20 - 2 * dyp;
        const bool live = (dyp < 21) && (y >= 0) && (y < 64);
        if (!live) continue;                     // wave-uniform

        f32x4 acc[9];
#pragma unroll
        for (int t2 = 0; t2 < 9; ++t2) acc[t2] = (f32x4)0.0f;

        // Per-lane A base; (Xi,ks) byte offset = Xi*8192 + ks*64.
        const short* Ap  = Ag + ((size_t)(b * 64 + y) * 96 + par * 48) * 256
                         + n * 256 + q * 8;
        const short* ap0 = Ap;
        const short* ap1 = Ap + 4096;
        const short* ap2 = Ap + 8192;

        // 4-deep rotating buffers, loads pinned via asm (12 in flight).
        bf16x8 a0[3], a1[3], a2[3], a3[3];
        GLOAD(a0[0], ap0, 0);   GLOAD(a0[1], ap1, 0);   GLOAD(a0[2], ap2, 0);
        GLOAD(a1[0], ap0, 64);  GLOAD(a1[1], ap1, 64);  GLOAD(a1[2], ap2, 64);
        GLOAD(a2[0], ap0, 128); GLOAD(a2[1], ap1, 128); GLOAD(a2[2], ap2, 128);
        GLOAD(a3[0], ap0, 192); GLOAD(a3[1], ap1, 192); GLOAD(a3[2], ap2, 192);

#define STEP(ks, ab, NW, PF) { \
        WAITV(NW); \
        const int ko = (ks) * 32 + q * 8; \
        bf16x8 b0 = *(const bf16x8*)&Bsh[(r0 * 256 + ko) ^ ((r0 & 7) << 3)]; if (!v0) b0 = 0; \
        bf16x8 b1 = *(const bf16x8*)&Bsh[(r1 * 256 + ko) ^ ((r1 & 7) << 3)]; \
        bf16x8 b2 = *(const bf16x8*)&Bsh[(r2 * 256 + ko) ^ ((r2 & 7) << 3)]; \
        bf16x8 b3 = *(const bf16x8*)&Bsh[(r3 * 256 + ko) ^ ((r3 & 7) << 3)]; if (!v3) b3 = 0; \
        acc[0] = __builtin_amdgcn_mfma_f32_16x16x32_bf16(ab[0], b0, acc[0], 0, 0, 0); \
        acc[1] = __builtin_amdgcn_mfma_f32_16x16x32_bf16(ab[0], b1, acc[1], 0, 0, 0); \
        acc[2] = __builtin_amdgcn_mfma_f32_16x16x32_bf16(ab[0], b2, acc[2], 0, 0, 0); \
        acc[3] = __builtin_amdgcn_mfma_f32_16x16x32_bf16(ab[1], b1, acc[3], 0, 0, 0); \
        acc[4] = __builtin_amdgcn_mfma_f32_16x16x32_bf16(ab[1], b2, acc[4], 0, 0, 0); \
        acc[5] = __builtin_amdgcn_mfma_f32_16x16x32_bf16(ab[1], b3, acc[5], 0, 0, 0); \
        acc[6] = __builtin_amdgcn_mfma_f32_16x16x32_bf16(ab[2], b2, acc[6], 0, 0, 0); \
        acc[7] = __builtin_amdgcn_mfma_f32_16x16x32_bf16(ab[2], b3, acc[7], 0, 0, 0); \
        if (PF) { \
            GLOAD(ab[0], ap0, ((ks) + 4) * 64); \
            GLOAD(ab[1], ap1, ((ks) + 4) * 64); \
            GLOAD(ab[2], ap2, ((ks) + 4) * 64); \
        } \
    }
        // acc[8] = (X2,U4): all B cols OOB -> stays zero (real zero outputs)

        STEP(0, a0, 9, 1) STEP(1, a1, 9, 1) STEP(2, a2, 9, 1) STEP(3, a3, 9, 1)
        STEP(4, a0, 9, 0) STEP(5, a1, 6, 0) STEP(6, a2, 3, 0) STEP(7, a3, 0, 0)
#undef STEP

        // wave-private scatter: sc[xe*21 + k]  (xe-major: <=2-way bank aliasing)
        const int mb = q * 4;
#pragma unroll
        for (int t2 = 0; t2 < 9; ++t2) {
            const int Xi = (t2 < 3) ? 0 : (t2 < 6 ? 1 : 2);
            constexpr int UJ[9] = {0, 1, 2, 1, 2, 3, 2, 3, 4};
            const int ub = UJ[t2] * 16;
#pragma unroll
            for (int rr = 0; rr < 4; ++rr) {
                const int xe = Xi * 16 + mb + rr;
                const int k  = ub + n - xe;
                if ((unsigned)k < 21u)
                    sc[xe * 21 + k] = acc[t2][rr];
            }
        }

        // wave-private store: gather 16 values first, then 16 stores.
        // k-major; stride-2, par sibling (same XCD now) fills the other
        // half of each line through L2.
        const size_t obase = ((size_t)(b * 441 + dyp * 21) * 64 + y) * 96 + par;
        float vals[16];
#pragma unroll
        for (int it = 0; it < 16; ++it) {
            const int e = it * 64 + lane;        // [0,1024), valid < 1008
            vals[it] = (e < 1008) ? sc[(e % 48) * 21 + (e / 48)] : 0.0f;
        }
#pragma unroll
        for (int it = 0; it < 16; ++it) {
            const int e = it * 64 + lane;
            if (e < 1008) {
                const int k  = e / 48;
                const int xe = e - k * 48;
                out[obase + (size_t)k * 6144 + 2 * xe] = vals[it] * (1.0f / 256.0f);
            }
        }
    }
}

extern "C" void kernel_launch(void* const* d_in, const int* in_sizes, int n_in,
                              void* d_out, int out_size, void* d_ws, size_t ws_size,
                              hipStream_t stream) {
    const float* in1 = (const float*)d_in[0];
    const float* in2 = (const float*)d_in[1];
    float* out = (float*)d_out;

    short* Ag = (short*)d_ws;                    // 256 planes * 24576 shorts = 12.58 MB
    short* Bg = Ag + (size_t)256 * PLANE;        // 12.58 MB

    corr_prepass<<<dim3(512), dim3(512), 0, stream>>>(in1, in2, Ag, Bg);
    corr_mfma<<<dim3(512), dim3(512), 0, stream>>>(Ag, Bg, out);
}

// Round 12
// 134.163 us; speedup vs baseline: 1.0121x; 1.0121x over previous
//
#include <hip/hip_runtime.h>

// Correlation via bf16 MFMA banded Gram.
// out[b, dyp*21+k, y, x] = (1/256) * sum_c in1[b,c,y,x] * in2[b,c,y+2(dyp-10), x+2(k-10)]
// Layouts (workspace): Ag/Bg[b*64+y][par*48+col][c] bf16, x = 2*col+par.
//
// R18 = R16 with both mechanisms repaired.
// (1) vmcnt counts stores too (R16 bug: WAITV(9) at round start drained the
//     previous round's 16 stores -> serialized rounds on HBM store retirement).
//     Fix: pre-issue next round's 12 A-loads BEFORE this round's stores, so the
//     steady queue is [L x12][S x16] with loads OLDEST; counted waits for loads
//     (25,25,25,25,9,6,3,0) never force store retirement. Prologue rounds use
//     (9,9,9,9,9,6,3,0). GLOAD has "memory" clobber so compiler stores can't
//     migrate across the asm and break the count math.
// (2) par-siblings were 256 dispatch slots apart -> half-dirty 64B output lines
//     evicted before the sibling wrote (WRITE 70.8MB = 2x). Fix: par in dispatch
//     bit0 (inner = y2lo<<1 | par) -> siblings 8 bhw apart, L2 write merge.
// Harness fact: 2x 42us fillBufferAligned (256MiB ws poison) = fixed 84us floor.

typedef short bf16x8 __attribute__((ext_vector_type(8)));
typedef float f32x4  __attribute__((ext_vector_type(4)));

#define PLANE 24576         // shorts per (b,y) plane: 96 rows * 256 c
#define ST    40            // prepass LDS row stride (shorts)

__device__ __forceinline__ short f2bf(float f) {
    union { float f; unsigned u; } x; x.f = f;
    const unsigned u = x.u;
    return (short)((u + 0x7fffu + ((u >> 16) & 1u)) >> 16);
}

// ---------- prepass: fp32 [b][c][y][x] -> bf16 [b*64+y][par*48+col][c] ----------
// block = (sel, b, ytile of 8, ctile of 32ch). Reads 3KB contiguous per channel.
__global__ __launch_bounds__(512)
void corr_prepass(const float* __restrict__ in1, const float* __restrict__ in2,
                  short* __restrict__ dstA, short* __restrict__ dstB) {
    const int bid = blockIdx.x;
    const int sel = bid >> 8;
    const int r   = bid & 255;
    const int b   = r >> 6;
    const int yt  = (r >> 3) & 7;
    const int ct  = r & 7;
    const int c0 = ct * 32, y0 = yt * 8;
    const float* src = sel ? in2 : in1;
    short* dst = sel ? dstB : dstA;

    __shared__ __align__(16) short T[768 * ST];   // [xx = yy*96+x][32c], 61.4 KB
    const int tid = threadIdx.x;

#pragma unroll
    for (int it = 0; it < 2; ++it) {
        const int d = it * 512 + tid;            // [0,1024), use d<768
        if (d < 768) {
            const int g = d / 192;               // channel octet 0..3
            const int f = d - g * 192;           // float4 index in 8y*96x chunk
            float4 v[8];
#pragma unroll
            for (int j = 0; j < 8; ++j) {
                const int c = c0 + g * 8 + j;
                v[j] = *(const float4*)(src + ((size_t)(b * 256 + c) * 64 + y0) * 96 + 4 * f);
            }
            bf16x8 w0, w1, w2, w3;
#pragma unroll
            for (int j = 0; j < 8; ++j) {
                w0[j] = f2bf(v[j].x); w1[j] = f2bf(v[j].y);
                w2[j] = f2bf(v[j].z); w3[j] = f2bf(v[j].w);
            }
            const int perm = ((g ^ (f & 3)) * 8);
            const int base = 4 * f * ST + perm;
            *(bf16x8*)&T[base]          = w0;
            *(bf16x8*)&T[base + ST]     = w1;
            *(bf16x8*)&T[base + 2*ST]   = w2;
            *(bf16x8*)&T[base + 3*ST]   = w3;
        }
    }
    __syncthreads();

#pragma unroll
    for (int it = 0; it < 6; ++it) {
        const int D  = it * 512 + tid;           // [0,3072)
        const int Rl = D >> 2, gp = D & 3;
        const int yy  = Rl / 96;
        const int rl  = Rl - yy * 96;
        const int par = rl / 48;
        const int col = rl - par * 48;
        const int x   = 2 * col + par;
        const int xx  = yy * 96 + x;
        const int perm = ((gp ^ ((xx >> 2) & 3)) * 8);
        const bf16x8 w = *(const bf16x8*)&T[xx * ST + perm];
        const size_t Rg = (size_t)(b * 64 + y0 + yy) * 96 + par * 48 + col;
        *(bf16x8*)(dst + Rg * 256 + c0 + gp * 8) = w;
    }
}

// asm A-load: 16B global load, immediate byte offset; dest pinned; "memory"
// clobber keeps compiler-emitted stores from migrating across (count safety).
#define GLOAD(dst, ptr, imm) \
    asm volatile("global_load_dwordx4 %0, %1, off offset:%c2" \
                 : "=&v"(dst) : "v"(ptr), "n"(imm) : "memory")

// counted wait + hard scheduling fence (rule #18: MFMA must not hoist above)
#define WAITV(N) \
    asm volatile("s_waitcnt vmcnt(" #N ")"); \
    __builtin_amdgcn_sched_barrier(0)

// ---------- main kernel: 512 threads = 8 waves = 8 slots, single par ----------
// Barrier-free rounds; wave-private scr; dyp = p*8 + slot, p in [0,3).
__global__ __launch_bounds__(512, 2)
void corr_mfma(const short* __restrict__ Ag, const short* __restrict__ Bg,
               float* __restrict__ out) {
    // XCD chunk = (b, y2-half); par in dispatch bit0 so par-siblings launch
    // ~adjacent and their half-line stores merge in L2.
    const int bhw = blockIdx.x;                  // [0,512)
    const int bid = ((bhw & 7) << 6) | (bhw >> 3);
    const int chunk = bid >> 6;                  // = XCD, [0,8)
    const int b    = chunk >> 1;
    const int yhi  = chunk & 1;
    const int inner = bid & 63;
    const int par  = inner & 1;
    const int y2   = (yhi << 5) | (inner >> 1);
    const int by2  = b * 64 + y2;

    const int tid  = threadIdx.x;
    const int lane = tid & 63, slot = tid >> 6;  // slot in [0,8)
    const int n    = lane & 15, q = lane >> 4;

    __shared__ __align__(16) short Bsh[48 * 256];    // 24576 B, XOR-swizzled rows
    __shared__ __align__(16) float scr[8][1008];     // 32256 B, per-wave, xe-major

    // stage B(b,y2) par-half ONCE (swizzle: short_idx ^= (row&7)<<3)
    {
        const short* src = Bg + (size_t)by2 * PLANE + par * 48 * 256;
#pragma unroll
        for (int it = 0; it < 3; ++it) {
            const int j   = it * 512 + tid;      // [0,1536)
            const int row = j >> 5;              // [0,48)
            const int ofs = (row * 256 + (j & 31) * 8) ^ ((row & 7) << 3);
            *(bf16x8*)&Bsh[ofs] = *(const bf16x8*)(src + j * 8);
        }
    }
    __syncthreads();   // compiler drains vmcnt+lgkmcnt here -> loop enters clean

    const bool v0 = (n >= 10), v3 = (n < 10);
    const int r0 = v0 ? (n - 10) : 0;
    const int r1 = n + 6;
    const int r2 = n + 22;
    const int r3 = v3 ? (n + 38) : 0;            // all in [0,48)

    float* const sc = scr[slot];

    bf16x8 a0[3], a1[3], a2[3], a3[3];
    bool piped = false;

#define LOAD12(P0, P1, P2) \
        GLOAD(a0[0], P0, 0);   GLOAD(a0[1], P1, 0);   GLOAD(a0[2], P2, 0);   \
        GLOAD(a1[0], P0, 64);  GLOAD(a1[1], P1, 64);  GLOAD(a1[2], P2, 64);  \
        GLOAD(a2[0], P0, 128); GLOAD(a2[1], P1, 128); GLOAD(a2[2], P2, 128); \
        GLOAD(a3[0], P0, 192); GLOAD(a3[1], P1, 192); GLOAD(a3[2], P2, 192);

#define STEP(ks, ab, NW, PF) { \
        WAITV(NW); \
        const int ko = (ks) * 32 + q * 8; \
        bf16x8 b0 = *(const bf16x8*)&Bsh[(r0 * 256 + ko) ^ ((r0 & 7) << 3)]; if (!v0) b0 = 0; \
        bf16x8 b1 = *(const bf16x8*)&Bsh[(r1 * 256 + ko) ^ ((r1 & 7) << 3)]; \
        bf16x8 b2 = *(const bf16x8*)&Bsh[(r2 * 256 + ko) ^ ((r2 & 7) << 3)]; \
        bf16x8 b3 = *(const bf16x8*)&Bsh[(r3 * 256 + ko) ^ ((r3 & 7) << 3)]; if (!v3) b3 = 0; \
        acc[0] = __builtin_amdgcn_mfma_f32_16x16x32_bf16(ab[0], b0, acc[0], 0, 0, 0); \
        acc[1] = __builtin_amdgcn_mfma_f32_16x16x32_bf16(ab[0], b1, acc[1], 0, 0, 0); \
        acc[2] = __builtin_amdgcn_mfma_f32_16x16x32_bf16(ab[0], b2, acc[2], 0, 0, 0); \
        acc[3] = __builtin_amdgcn_mfma_f32_16x16x32_bf16(ab[1], b1, acc[3], 0, 0, 0); \
        acc[4] = __builtin_amdgcn_mfma_f32_16x16x32_bf16(ab[1], b2, acc[4], 0, 0, 0); \
        acc[5] = __builtin_amdgcn_mfma_f32_16x16x32_bf16(ab[1], b3, acc[5], 0, 0, 0); \
        acc[6] = __builtin_amdgcn_mfma_f32_16x16x32_bf16(ab[2], b2, acc[6], 0, 0, 0); \
        acc[7] = __builtin_amdgcn_mfma_f32_16x16x32_bf16(ab[2], b3, acc[7], 0, 0, 0); \
        if (PF) { \
            GLOAD(ab[0], ap0, ((ks) + 4) * 64); \
            GLOAD(ab[1], ap1, ((ks) + 4) * 64); \
            GLOAD(ab[2], ap2, ((ks) + 4) * 64); \
        } \
    }
    // acc[8] = (X2,U4): all B cols OOB -> stays zero (real zero outputs)

#pragma unroll
    for (int p = 0; p < 3; ++p) {
        const int dyp = p * 8 + slot;
        const int y   = y2 + 20 - 2 * dyp;
        const bool live = (dyp < 21) && (y >= 0) && (y < 64);
        if (!live) { piped = false; continue; }  // wave-uniform

        // Per-lane A base; (Xi,ks) byte offset = Xi*8192 + ks*64.
        const short* Ap  = Ag + ((size_t)(b * 64 + y) * 96 + par * 48) * 256
                         + n * 256 + q * 8;
        const short* ap0 = Ap;
        const short* ap1 = Ap + 4096;
        const short* ap2 = Ap + 8192;

        if (!piped) { LOAD12(ap0, ap1, ap2) }    // prologue issue (ks0-3)

        f32x4 acc[9];
#pragma unroll
        for (int t2 = 0; t2 < 9; ++t2) acc[t2] = (f32x4)0.0f;

        if (piped) {
            // queue: [L x12 oldest][S x16] -> load waits never drain stores
            STEP(0, a0, 25, 1) STEP(1, a1, 25, 1) STEP(2, a2, 25, 1) STEP(3, a3, 25, 1)
            STEP(4, a0,  9, 0) STEP(5, a1,  6, 0) STEP(6, a2,  3, 0) STEP(7, a3,  0, 0)
        } else {
            STEP(0, a0,  9, 1) STEP(1, a1,  9, 1) STEP(2, a2,  9, 1) STEP(3, a3,  9, 1)
            STEP(4, a0,  9, 0) STEP(5, a1,  6, 0) STEP(6, a2,  3, 0) STEP(7, a3,  0, 0)
        }

        // pre-issue NEXT round's 12 loads BEFORE this round's stores
        {
            const int yn = y - 16;               // yn<48<64 automatically
            const bool live_n = (p < 2) && ((dyp + 8) < 21) && (yn >= 0);
            if (live_n) {
                const short* bp0 = ap0 - 393216; // -16*96*256 shorts
                const short* bp1 = ap1 - 393216;
                const short* bp2 = ap2 - 393216;
                LOAD12(bp0, bp1, bp2)
                piped = true;
            } else {
                piped = false;
            }
        }

        // wave-private scatter: sc[xe*21 + k]  (xe-major: <=2-way bank aliasing)
        const int mb = q * 4;
#pragma unroll
        for (int t2 = 0; t2 < 9; ++t2) {
            const int Xi = (t2 < 3) ? 0 : (t2 < 6 ? 1 : 2);
            constexpr int UJ[9] = {0, 1, 2, 1, 2, 3, 2, 3, 4};
            const int ub = UJ[t2] * 16;
#pragma unroll
            for (int rr = 0; rr < 4; ++rr) {
                const int xe = Xi * 16 + mb + rr;
                const int k  = ub + n - xe;
                if ((unsigned)k < 21u)
                    sc[xe * 21 + k] = acc[t2][rr];
            }
        }

        // wave-private store: gather 16 values first, then 16 stores (exactly 16
        // vmem stores/wave -> count math). k-major; stride-2; par sibling
        // (adjacent dispatch now) fills the other half of each line in L2.
        const size_t obase = ((size_t)(b * 441 + dyp * 21) * 64 + y) * 96 + par;
        float vals[16];
#pragma unroll
        for (int it = 0; it < 16; ++it) {
            const int e = it * 64 + lane;        // [0,1024), valid < 1008
            vals[it] = (e < 1008) ? sc[(e % 48) * 21 + (e / 48)] : 0.0f;
        }
#pragma unroll
        for (int it = 0; it < 16; ++it) {
            const int e = it * 64 + lane;
            if (e < 1008) {
                const int k  = e / 48;
                const int xe = e - k * 48;
                out[obase + (size_t)k * 6144 + 2 * xe] = vals[it] * (1.0f / 256.0f);
            }
        }
    }
#undef STEP
#undef LOAD12
}

extern "C" void kernel_launch(void* const* d_in, const int* in_sizes, int n_in,
                              void* d_out, int out_size, void* d_ws, size_t ws_size,
                              hipStream_t stream) {
    const float* in1 = (const float*)d_in[0];
    const float* in2 = (const float*)d_in[1];
    float* out = (float*)d_out;

    short* Ag = (short*)d_ws;                    // 256 planes * 24576 shorts = 12.58 MB
    short* Bg = Ag + (size_t)256 * PLANE;        // 12.58 MB

    corr_prepass<<<dim3(512), dim3(512), 0, stream>>>(in1, in2, Ag, Bg);
    corr_mfma<<<dim3(512), dim3(512), 0, stream>>>(Ag, Bg, out);
}